// Round 4
// baseline (361.974 us; speedup 1.0000x reference)
//
#include <hip/hip_runtime.h>
#include <math.h>

// Problem constants (fixed by reference setup_inputs)
#define B_ 16
#define C_ 512
#define N_ 4096   // 64*64
#define K_ 64

// Workspace layout (float offsets). Total ~2.27M floats = 9.1 MB.
#define OFF_PBIG    0         // [64 k][2048 dw] bf16-pair packed param matrix (r = c*8+f)
#define OFF_CONST   131072    // [K] fp32 sum_c a^2/s^2
#define OFF_INVSIG  131136    // [K][C] 1/sigma fp32
#define OFF_WSUM    163904    // [B][K]
#define OFF_GSUM    164928    // [B]
#define OFF_WXP     165120    // [4 nt][B][K][C] fp32 partials (8 MB)

typedef short bf16x8 __attribute__((ext_vector_type(8)));   // 8 bf16 in 4 VGPRs
typedef float f32x16 __attribute__((ext_vector_type(16)));  // MFMA 32x32 accumulator

union U4 { uint4 u; bf16x8 b; };

__device__ __forceinline__ unsigned hi16(float f) { return __float_as_uint(f) >> 16; }
__device__ __forceinline__ float fromhi(unsigned h) { return __uint_as_float(h << 16); }
// pack two floats' truncated-bf16 into one dword: low16 = bf16(lo), high16 = bf16(hi)
__device__ __forceinline__ unsigned pk(float lo, float hi) {
  return (__float_as_uint(lo) >> 16) | (__float_as_uint(hi) & 0xFFFF0000u);
}

// ---------------------------------------------------------------- kernel 1
// Build pbig (A-matrix, inner slots per c: {is2h,is2l | is2h,mh | ml,mh | 0,0}),
// constk fp32, invsig; zero wsum/gsum. One block per k.
__global__ void k_prep(const float* __restrict__ anchor,
                       const float* __restrict__ sraw,
                       unsigned* __restrict__ pbig,
                       float* __restrict__ constk,
                       float* __restrict__ invsig,
                       float* __restrict__ wsum,
                       float* __restrict__ gsum) {
  const int k = blockIdx.x;
  const int t = threadIdx.x;
  __shared__ float s_is2[C_], s_m[C_];
  __shared__ float red[4];
  float part = 0.f;
#pragma unroll
  for (int r = 0; r < 2; r++) {
    int c = r * 256 + t;
    float a = anchor[k * C_ + c];
    float sg = 1.f / (1.f + __expf(-sraw[k * C_ + c]));
    float is = 1.f / sg;
    float is2 = is * is;
    s_is2[c] = is2;
    s_m[c] = -2.f * a * is2;
    invsig[k * C_ + c] = is;
    part = fmaf(a * a, is2, part);
  }
  float v = part;
#pragma unroll
  for (int off = 32; off; off >>= 1) v += __shfl_down(v, off);
  if ((t & 63) == 0) red[t >> 6] = v;
  __syncthreads();
  if (t == 0) constk[k] = red[0] + red[1] + red[2] + red[3];
#pragma unroll
  for (int r = 0; r < 2; r++) {
    int c = r * 256 + t;
    float is2 = s_is2[c], m = s_m[c];
    unsigned ih = hi16(is2);
    unsigned il = hi16(is2 - fromhi(ih));
    unsigned mh = hi16(m);
    unsigned ml = hi16(m - fromhi(mh));
    unsigned* p = pbig + (size_t)k * 2048 + c * 4;
    p[0] = ih | (il << 16);
    p[1] = ih | (mh << 16);
    p[2] = ml | (mh << 16);
    p[3] = 0u;
  }
  if (k == 0) {
    for (int i = t; i < B_ * K_; i += 256) wsum[i] = 0.f;
    if (t < B_) gsum[t] = 0.f;
  }
}

// ---------------------------------------------------------------- kernel 2
// MFMA distance GEMM (split-bf16, inner dim 4096) + in-register softmax.
// grid (N/128, B), block 256 (4 waves). Wave tile: 64k x 32n.
// Chunk-ahead register prefetch of pbig (LDS-staged) and x (consumed direct).
__global__ __launch_bounds__(256) void k_dist(
    const float* __restrict__ x,
    const unsigned* __restrict__ pbig,
    const float* __restrict__ constk,
    float* __restrict__ soft,
    float* __restrict__ wsum) {
  const int b = blockIdx.y;
  const int tid = threadIdx.x;
  const int wid = tid >> 6, lane = tid & 63, l31 = lane & 31, lh = lane >> 5;
  const int n0 = blockIdx.x * 128 + wid * 32;
  __shared__ unsigned ldsA[64 * 132];  // row stride 132 dw (proven conflict-free)
  __shared__ float csh[64];
  if (tid < 64) csh[tid] = constk[tid];

  f32x16 acc[2];
#pragma unroll
  for (int kt = 0; kt < 2; kt++)
#pragma unroll
    for (int i = 0; i < 16; i++) acc[kt][i] = 0.f;

  const float* xb = x + (size_t)b * (C_ * N_);
  const uint4* src = (const uint4*)pbig;

  uint4 preg[8];
#pragma unroll
  for (int it = 0; it < 8; it++) {
    int flat = tid + it * 256;
    preg[it] = src[(size_t)(flat >> 5) * 512 + (flat & 31)];
  }
  float xcur[16], xnext[16];
#pragma unroll
  for (int i = 0; i < 16; i++)
    xcur[i] = xb[(size_t)(i * 2 + lh) * N_ + n0 + l31];

  for (int chunk = 0; chunk < 16; chunk++) {
#pragma unroll
    for (int it = 0; it < 8; it++) {
      int flat = tid + it * 256;
      *(uint4*)&ldsA[(flat >> 5) * 132 + (flat & 31) * 4] = preg[it];
    }
    __syncthreads();
    if (chunk < 15) {
#pragma unroll
      for (int it = 0; it < 8; it++) {
        int flat = tid + it * 256;
        preg[it] = src[(size_t)(flat >> 5) * 512 + (chunk + 1) * 32 + (flat & 31)];
      }
#pragma unroll
      for (int i = 0; i < 16; i++)
        xnext[i] = xb[(size_t)((chunk + 1) * 32 + i * 2 + lh) * N_ + n0 + l31];
    }
#pragma unroll
    for (int kstep = 0; kstep < 16; kstep++) {
      U4 a0, a1;
      a0.u = *(const uint4*)&ldsA[l31 * 132 + kstep * 8 + lh * 4];
      a1.u = *(const uint4*)&ldsA[(32 + l31) * 132 + kstep * 8 + lh * 4];
      float xv = xcur[kstep];
      float x2 = xv * xv;
      unsigned u = __float_as_uint(xv);
      unsigned u2 = __float_as_uint(x2);
      unsigned uhf = u & 0xFFFF0000u;
      unsigned u2hf = u2 & 0xFFFF0000u;
      float xl = xv - __uint_as_float(uhf);
      float x2l = x2 - __uint_as_float(u2hf);
      U4 bf;
      bf.u.x = (u2 >> 16) | u2hf;                       // x2h | x2h
      bf.u.y = (__float_as_uint(x2l) >> 16) | uhf;      // x2l | xh
      bf.u.z = (u >> 16) | (__float_as_uint(xl) & 0xFFFF0000u);  // xh | xl
      bf.u.w = 0u;
      acc[0] = __builtin_amdgcn_mfma_f32_32x32x16_bf16(a0.b, bf.b, acc[0], 0, 0, 0);
      acc[1] = __builtin_amdgcn_mfma_f32_32x32x16_bf16(a1.b, bf.b, acc[1], 0, 0, 0);
    }
    __syncthreads();
#pragma unroll
    for (int i = 0; i < 16; i++) xcur[i] = xnext[i];
  }

  // ---- softmax over k=64 per column n (lane l & l^32 hold complementary k) ----
  float mm = -3.4e38f;
#pragma unroll
  for (int kt = 0; kt < 2; kt++)
#pragma unroll
    for (int r = 0; r < 16; r++) {
      int k = kt * 32 + (r & 3) + 8 * (r >> 2) + 4 * lh;
      float l = -0.5f * (acc[kt][r] + csh[k]);
      acc[kt][r] = l;
      mm = fmaxf(mm, l);
    }
  mm = fmaxf(mm, __shfl_xor(mm, 32));
  float ss = 0.f;
#pragma unroll
  for (int kt = 0; kt < 2; kt++)
#pragma unroll
    for (int r = 0; r < 16; r++) {
      float e = __expf(acc[kt][r] - mm);
      acc[kt][r] = e;
      ss += e;
    }
  ss += __shfl_xor(ss, 32);
  float inv = 1.f / ss;

  float* softb = soft + (size_t)b * (K_ * N_);
#pragma unroll
  for (int kt = 0; kt < 2; kt++)
#pragma unroll
    for (int r = 0; r < 16; r++) {
      float w = acc[kt][r] * inv;
      acc[kt][r] = w;
      int k = kt * 32 + (r & 3) + 8 * (r >> 2) + 4 * lh;
      softb[(size_t)k * N_ + n0 + l31] = w;
    }
  // ---- wsum ----
#pragma unroll
  for (int kt = 0; kt < 2; kt++)
#pragma unroll
    for (int r = 0; r < 16; r++) {
      float v = acc[kt][r];
      v += __shfl_xor(v, 1);
      v += __shfl_xor(v, 2);
      v += __shfl_xor(v, 4);
      v += __shfl_xor(v, 8);
      v += __shfl_xor(v, 16);
      if (l31 == 0) {
        int k = kt * 32 + (r & 3) + 8 * (r >> 2) + 4 * lh;
        atomicAdd(&wsum[b * K_ + k], v);
      }
    }
}

// ---------------------------------------------------------------- kernel 3
// Aggregation GEMM via MFMA, LDS-staged coalesced loads, no atomics.
// grid (C/128, 4 nt, B), block 256. Block: 64k x 128c over n-range 1024.
// Wave w owns c-sub w*32. Partials to wxp[nt].
__global__ __launch_bounds__(256) void k_agg(const float* __restrict__ x,
                                             const float* __restrict__ soft,
                                             float* __restrict__ wxp) {
  const int ct = blockIdx.x;
  const int nt = blockIdx.y;
  const int b = blockIdx.z;
  const int tid = threadIdx.x;
  const int wid = tid >> 6, lane = tid & 63, l31 = lane & 31, lh = lane >> 5;
  __shared__ unsigned sA[64 * 36];    // soft bf16-pairs [k][32 dw + 4 pad]
  __shared__ unsigned sX[128 * 36];   // x bf16-pairs [c][32 dw + 4 pad]

  f32x16 acc[2];
#pragma unroll
  for (int kt = 0; kt < 2; kt++)
#pragma unroll
    for (int i = 0; i < 16; i++) acc[kt][i] = 0.f;

  const float* sb = soft + (size_t)b * (K_ * N_) + nt * 1024;
  const float* xg = x + ((size_t)b * C_ + ct * 128) * N_ + nt * 1024;
  const int srow = tid >> 2, scol = (tid & 3) * 16;   // soft: 4 thr/row
  const int xrow = tid >> 1, xcol = (tid & 1) * 32;   // x: 2 thr/row

  float4 sreg[4], xreg[8];
#pragma unroll
  for (int q = 0; q < 4; q++)
    sreg[q] = *(const float4*)&sb[(size_t)srow * N_ + scol + q * 4];
#pragma unroll
  for (int q = 0; q < 8; q++)
    xreg[q] = *(const float4*)&xg[(size_t)xrow * N_ + xcol + q * 4];

  for (int ch = 0; ch < 16; ch++) {
    {
      uint4 w0 = make_uint4(pk(sreg[0].x, sreg[0].y), pk(sreg[0].z, sreg[0].w),
                            pk(sreg[1].x, sreg[1].y), pk(sreg[1].z, sreg[1].w));
      uint4 w1 = make_uint4(pk(sreg[2].x, sreg[2].y), pk(sreg[2].z, sreg[2].w),
                            pk(sreg[3].x, sreg[3].y), pk(sreg[3].z, sreg[3].w));
      *(uint4*)&sA[srow * 36 + (tid & 3) * 8] = w0;
      *(uint4*)&sA[srow * 36 + (tid & 3) * 8 + 4] = w1;
#pragma unroll
      for (int h = 0; h < 4; h++) {
        uint4 v = make_uint4(
            pk(xreg[h * 2].x, xreg[h * 2].y), pk(xreg[h * 2].z, xreg[h * 2].w),
            pk(xreg[h * 2 + 1].x, xreg[h * 2 + 1].y),
            pk(xreg[h * 2 + 1].z, xreg[h * 2 + 1].w));
        *(uint4*)&sX[xrow * 36 + (tid & 1) * 16 + h * 4] = v;
      }
    }
    __syncthreads();
    if (ch < 15) {
      int base = (ch + 1) * 64;
#pragma unroll
      for (int q = 0; q < 4; q++)
        sreg[q] = *(const float4*)&sb[(size_t)srow * N_ + base + scol + q * 4];
#pragma unroll
      for (int q = 0; q < 8; q++)
        xreg[q] = *(const float4*)&xg[(size_t)xrow * N_ + base + xcol + q * 4];
    }
#pragma unroll
    for (int kk = 0; kk < 4; kk++) {
      U4 a0, a1, bf;
      a0.u = *(const uint4*)&sA[l31 * 36 + kk * 8 + lh * 4];
      a1.u = *(const uint4*)&sA[(32 + l31) * 36 + kk * 8 + lh * 4];
      bf.u = *(const uint4*)&sX[(wid * 32 + l31) * 36 + kk * 8 + lh * 4];
      acc[0] = __builtin_amdgcn_mfma_f32_32x32x16_bf16(a0.b, bf.b, acc[0], 0, 0, 0);
      acc[1] = __builtin_amdgcn_mfma_f32_32x32x16_bf16(a1.b, bf.b, acc[1], 0, 0, 0);
    }
    __syncthreads();
  }
  float* outp = wxp + (((size_t)nt * B_ + b) * K_) * C_ + ct * 128 + wid * 32 + l31;
#pragma unroll
  for (int kt = 0; kt < 2; kt++)
#pragma unroll
    for (int r = 0; r < 16; r++) {
      int k = kt * 32 + (r & 3) + 8 * (r >> 2) + 4 * lh;
      outp[(size_t)k * C_] = acc[kt][r];
    }
}

// ---------------------------------------------------------------- kernel 4
// Sum 4 partials; nodes = (wx - wsum*a)/sigma/(wsum+eps); intra L2-norm; gsum.
__global__ void k_nodes(const float* __restrict__ wxp,
                        const float* __restrict__ wsum,
                        const float* __restrict__ anchor,
                        const float* __restrict__ invsig,
                        float* __restrict__ out0,
                        float* __restrict__ gsum) {
  const int k = blockIdx.x, b = blockIdx.y;
  const int tid = threadIdx.x;
  float wsv = wsum[b * K_ + k];
  float winv = 1.f / (wsv + 1e-9f);
  float vals[4];
  float local = 0.f;
#pragma unroll
  for (int r = 0; r < 4; r++) {
    int c = r * 128 + tid;
    float w = 0.f;
#pragma unroll
    for (int p = 0; p < 4; p++)
      w += wxp[(((size_t)p * B_ + b) * K_ + k) * C_ + c];
    float v = (w - wsv * anchor[k * C_ + c]) * invsig[k * C_ + c] * winv;
    vals[r] = v;
    local = fmaf(v, v, local);
  }
  float v = local;
#pragma unroll
  for (int off = 32; off; off >>= 1) v += __shfl_down(v, off);
  __shared__ float red[2];
  if ((tid & 63) == 0) red[tid >> 6] = v;
  __syncthreads();
  float sumsq = red[0] + red[1];
  float norm = sqrtf(sumsq);
  float scale = 1.f / fmaxf(norm, 1e-12f);
#pragma unroll
  for (int r = 0; r < 4; r++) {
    int c = r * 128 + tid;
    out0[((size_t)b * K_ + k) * C_ + c] = vals[r] * scale;
  }
  if (tid == 0) atomicAdd(&gsum[b], sumsq * scale * scale);
}

// ---------------------------------------------------------------- kernel 5
// Global L2 scale in place on out0 ([B][K*C] flat == reference (B,C,K)).
__global__ void k_final(float* __restrict__ out0,
                        const float* __restrict__ gsum) {
  for (int i = blockIdx.x * 256 + threadIdx.x; i < B_ * K_ * C_;
       i += gridDim.x * 256) {
    int b = i >> 15;  // K_*C_ = 32768
    out0[i] = out0[i] * (1.f / fmaxf(sqrtf(gsum[b]), 1e-12f));
  }
}

// ---------------------------------------------------------------- launch
extern "C" void kernel_launch(void* const* d_in, const int* in_sizes, int n_in,
                              void* d_out, int out_size, void* d_ws, size_t ws_size,
                              hipStream_t stream) {
  const float* x = (const float*)d_in[0];       // [B,C,H,W]
  const float* anchor = (const float*)d_in[1];  // [K,C]
  const float* sraw = (const float*)d_in[2];    // [K,C]
  float* out0 = (float*)d_out;                          // [B,C,K] flat
  float* soft = out0 + (size_t)B_ * C_ * K_;            // [B,K,N] (output 1)
  float* ws = (float*)d_ws;

  unsigned* pbig = (unsigned*)(ws + OFF_PBIG);
  float* constk = ws + OFF_CONST;
  float* invsig = ws + OFF_INVSIG;
  float* wsum = ws + OFF_WSUM;
  float* gsum = ws + OFF_GSUM;
  float* wxp = ws + OFF_WXP;

  k_prep<<<K_, 256, 0, stream>>>(anchor, sraw, pbig, constk, invsig, wsum, gsum);
  k_dist<<<dim3(N_ / 128, B_), 256, 0, stream>>>(x, pbig, constk, soft, wsum);
  k_agg<<<dim3(C_ / 128, 4, B_), 256, 0, stream>>>(x, soft, wxp);
  k_nodes<<<dim3(K_, B_), 128, 0, stream>>>(wxp, wsum, anchor, invsig, out0,
                                            gsum);
  k_final<<<512, 256, 0, stream>>>(out0, gsum);
}

// Round 5
// 347.500 us; speedup vs baseline: 1.0417x; 1.0417x over previous
//
#include <hip/hip_runtime.h>
#include <math.h>

// Problem constants (fixed by reference setup_inputs)
#define B_ 16
#define C_ 512
#define N_ 4096   // 64*64
#define K_ 64

// Workspace layout (float offsets). Total ~9.05 MB (round-4 proved 9.1 MB OK).
#define OFF_PBIG    0         // [64 k][2048 dw] bf16-pair packed param matrix
#define OFF_CONST   131072    // [K] fp32 sum_c a^2/s^2
#define OFF_INVSIG  131136    // [K][C] 1/sigma fp32
#define OFF_WSUM    163904    // [B][K]
#define OFF_GSUM    164928    // [B]
#define OFF_WXP     165120    // [8 nt][B][K][C] bf16 partials (8.4 MB as ushort)

typedef short bf16x8 __attribute__((ext_vector_type(8)));   // 8 bf16 in 4 VGPRs
typedef float f32x16 __attribute__((ext_vector_type(16)));  // MFMA 32x32 accumulator

union U4 { uint4 u; bf16x8 b; };

__device__ __forceinline__ unsigned hi16(float f) { return __float_as_uint(f) >> 16; }
__device__ __forceinline__ float fromhi(unsigned h) { return __uint_as_float(h << 16); }
// pack two floats' truncated-bf16 into one dword: low16 = bf16(lo), high16 = bf16(hi)
__device__ __forceinline__ unsigned pk(float lo, float hi) {
  return (__float_as_uint(lo) >> 16) | (__float_as_uint(hi) & 0xFFFF0000u);
}
// single float -> bf16 (RNE) as ushort
__device__ __forceinline__ unsigned short bf16r(float f) {
  unsigned u = __float_as_uint(f);
  u += 0x7FFFu + ((u >> 16) & 1u);
  return (unsigned short)(u >> 16);
}

// async global->LDS, 4B per lane (zero VGPR staging cost)
#if defined(__has_builtin) && __has_builtin(__builtin_amdgcn_global_load_lds)
#define GLD4(g, l)                                              \
  __builtin_amdgcn_global_load_lds(                             \
      (const __attribute__((address_space(1))) void*)(g),       \
      (__attribute__((address_space(3))) void*)(l), 4, 0, 0)
#else
#define GLD4(g, l) (*(l) = *(g))   // sync fallback (correct, slower)
#endif

// ---------------------------------------------------------------- kernel 1
// Build pbig (per c slots: {is2h,is2l | is2h,mh | ml,mh | 0,0}), constk,
// invsig; zero wsum/gsum. One block per k.
__global__ void k_prep(const float* __restrict__ anchor,
                       const float* __restrict__ sraw,
                       unsigned* __restrict__ pbig,
                       float* __restrict__ constk,
                       float* __restrict__ invsig,
                       float* __restrict__ wsum,
                       float* __restrict__ gsum) {
  const int k = blockIdx.x;
  const int t = threadIdx.x;
  __shared__ float s_is2[C_], s_m[C_];
  __shared__ float red[4];
  float part = 0.f;
#pragma unroll
  for (int r = 0; r < 2; r++) {
    int c = r * 256 + t;
    float a = anchor[k * C_ + c];
    float sg = 1.f / (1.f + __expf(-sraw[k * C_ + c]));
    float is = 1.f / sg;
    float is2 = is * is;
    s_is2[c] = is2;
    s_m[c] = -2.f * a * is2;
    invsig[k * C_ + c] = is;
    part = fmaf(a * a, is2, part);
  }
  float v = part;
#pragma unroll
  for (int off = 32; off; off >>= 1) v += __shfl_down(v, off);
  if ((t & 63) == 0) red[t >> 6] = v;
  __syncthreads();
  if (t == 0) constk[k] = red[0] + red[1] + red[2] + red[3];
#pragma unroll
  for (int r = 0; r < 2; r++) {
    int c = r * 256 + t;
    float is2 = s_is2[c], m = s_m[c];
    unsigned ih = hi16(is2);
    unsigned il = hi16(is2 - fromhi(ih));
    unsigned mh = hi16(m);
    unsigned ml = hi16(m - fromhi(mh));
    unsigned* p = pbig + (size_t)k * 2048 + c * 4;
    p[0] = ih | (il << 16);
    p[1] = ih | (mh << 16);
    p[2] = ml | (mh << 16);
    p[3] = 0u;
  }
  if (k == 0) {
    for (int i = t; i < B_ * K_; i += 256) wsum[i] = 0.f;
    if (t < B_) gsum[t] = 0.f;
  }
}

// ---------------------------------------------------------------- kernel 2
// MFMA distance GEMM (split-bf16) + in-register softmax.
// grid (N/128, B), block 256 (4 waves). Wave tile 64k x 32n.
// x staged async global->LDS (double-buffered); pbig 16-c chunks via 16 VGPRs.
__global__ __launch_bounds__(256) void k_dist(
    const float* __restrict__ x,
    const unsigned* __restrict__ pbig,
    const float* __restrict__ constk,
    float* __restrict__ soft,
    float* __restrict__ wsum) {
  const int b = blockIdx.y;
  const int nblk = blockIdx.x * 128;
  const int tid = threadIdx.x;
  const int wid = tid >> 6, lane = tid & 63, l31 = lane & 31, lh = lane >> 5;
  const int nw = nblk + wid * 32;

  __shared__ unsigned ldsA[64 * 68];   // 16-c chunk, stride 68 dw (17.4 KB)
  __shared__ float ldsX[2][16 * 128];  // x chunk [16c][128n] x2   (16.4 KB)
  __shared__ float csh[64];
  if (tid < 64) csh[tid] = constk[tid];

  f32x16 acc[2];
#pragma unroll
  for (int kt = 0; kt < 2; kt++)
#pragma unroll
    for (int i = 0; i < 16; i++) acc[kt][i] = 0.f;

  const float* xb = x + (size_t)b * (C_ * N_);
  const uint4* src = (const uint4*)pbig;

  uint4 preg[4];
  // ---- preload chunk 0 ----
#pragma unroll
  for (int it = 0; it < 8; it++) {
    int f = it * 256 + tid;
    GLD4(xb + (size_t)(f >> 7) * N_ + nblk + (f & 127), &ldsX[0][f]);
  }
#pragma unroll
  for (int it = 0; it < 4; it++) {
    int f = it * 256 + tid;
    preg[it] = src[(size_t)(f >> 4) * 512 + (f & 15)];
  }

  for (int chunk = 0; chunk < 32; chunk++) {
    __syncthreads();   // A: drains async x[chunk] + preg; ldsA free
#pragma unroll
    for (int it = 0; it < 4; it++) {
      int f = it * 256 + tid;
      *(uint4*)&ldsA[(f >> 4) * 68 + (f & 15) * 4] = preg[it];
    }
    __syncthreads();   // B: ldsA visible (no vmem in flight -> cheap drain)
    if (chunk < 31) {
      const int nc = chunk + 1;
#pragma unroll
      for (int it = 0; it < 8; it++) {
        int f = it * 256 + tid;
        GLD4(xb + (size_t)(nc * 16 + (f >> 7)) * N_ + nblk + (f & 127),
             &ldsX[nc & 1][f]);
      }
#pragma unroll
      for (int it = 0; it < 4; it++) {
        int f = it * 256 + tid;
        preg[it] = src[(size_t)(f >> 4) * 512 + nc * 16 + (f & 15)];
      }
    }
    const float* xc = &ldsX[chunk & 1][0];
#pragma unroll
    for (int kstep = 0; kstep < 8; kstep++) {
      U4 a0, a1;
      a0.u = *(const uint4*)&ldsA[l31 * 68 + kstep * 8 + lh * 4];
      a1.u = *(const uint4*)&ldsA[(32 + l31) * 68 + kstep * 8 + lh * 4];
      float xv = xc[(kstep * 2 + lh) * 128 + wid * 32 + l31];
      float x2 = xv * xv;
      unsigned u = __float_as_uint(xv);
      unsigned u2 = __float_as_uint(x2);
      unsigned uhf = u & 0xFFFF0000u;
      unsigned u2hf = u2 & 0xFFFF0000u;
      float xl = xv - __uint_as_float(uhf);
      float x2l = x2 - __uint_as_float(u2hf);
      U4 bf;
      bf.u.x = (u2 >> 16) | u2hf;                                 // x2h | x2h
      bf.u.y = (__float_as_uint(x2l) >> 16) | uhf;                // x2l | xh
      bf.u.z = (u >> 16) | (__float_as_uint(xl) & 0xFFFF0000u);   // xh  | xl
      bf.u.w = 0u;
      acc[0] = __builtin_amdgcn_mfma_f32_32x32x16_bf16(a0.b, bf.b, acc[0], 0, 0, 0);
      acc[1] = __builtin_amdgcn_mfma_f32_32x32x16_bf16(a1.b, bf.b, acc[1], 0, 0, 0);
    }
  }

  // ---- softmax over k=64 per column n (lane l & l^32 hold complementary k) ----
  float mm = -3.4e38f;
#pragma unroll
  for (int kt = 0; kt < 2; kt++)
#pragma unroll
    for (int r = 0; r < 16; r++) {
      int k = kt * 32 + (r & 3) + 8 * (r >> 2) + 4 * lh;
      float l = -0.5f * (acc[kt][r] + csh[k]);
      acc[kt][r] = l;
      mm = fmaxf(mm, l);
    }
  mm = fmaxf(mm, __shfl_xor(mm, 32));
  float ss = 0.f;
#pragma unroll
  for (int kt = 0; kt < 2; kt++)
#pragma unroll
    for (int r = 0; r < 16; r++) {
      float e = __expf(acc[kt][r] - mm);
      acc[kt][r] = e;
      ss += e;
    }
  ss += __shfl_xor(ss, 32);
  float inv = 1.f / ss;

  float* softb = soft + (size_t)b * (K_ * N_);
#pragma unroll
  for (int kt = 0; kt < 2; kt++)
#pragma unroll
    for (int r = 0; r < 16; r++) {
      float w = acc[kt][r] * inv;
      acc[kt][r] = w;
      int k = kt * 32 + (r & 3) + 8 * (r >> 2) + 4 * lh;
      softb[(size_t)k * N_ + nw + l31] = w;
    }
  // ---- wsum ----
#pragma unroll
  for (int kt = 0; kt < 2; kt++)
#pragma unroll
    for (int r = 0; r < 16; r++) {
      float v = acc[kt][r];
      v += __shfl_xor(v, 1);
      v += __shfl_xor(v, 2);
      v += __shfl_xor(v, 4);
      v += __shfl_xor(v, 8);
      v += __shfl_xor(v, 16);
      if (l31 == 0) {
        int k = kt * 32 + (r & 3) + 8 * (r >> 2) + 4 * lh;
        atomicAdd(&wsum[b * K_ + k], v);
      }
    }
}

// ---------------------------------------------------------------- kernel 3
// Aggregation GEMM via MFMA: wx[b,k,c] = sum_n soft[b,k,n]*x[b,c,n].
// grid (C/128, 8 nt, B) = 512, block 256. Quarter-wave coalesced staging,
// bf16 RNE partials, no atomics.
__global__ __launch_bounds__(256) void k_agg(const float* __restrict__ x,
                                             const float* __restrict__ soft,
                                             unsigned short* __restrict__ wxp) {
  const int ct = blockIdx.x, nt = blockIdx.y, b = blockIdx.z;
  const int tid = threadIdx.x;
  const int wid = tid >> 6, lane = tid & 63, l31 = lane & 31, lh = lane >> 5;
  __shared__ unsigned sA[64 * 36];    // soft bf16-pairs [k][32dw + 4 pad]
  __shared__ unsigned sX[128 * 36];   // x bf16-pairs [c][32dw + 4 pad]

  f32x16 acc[2];
#pragma unroll
  for (int kt = 0; kt < 2; kt++)
#pragma unroll
    for (int i = 0; i < 16; i++) acc[kt][i] = 0.f;

  const float* sb = soft + (size_t)b * (K_ * N_) + nt * 512;
  const float* xg = x + ((size_t)b * C_ + ct * 128) * N_ + nt * 512;
  const int row16 = tid >> 4, col4 = tid & 15;   // 16 lanes x 16B = 256B/row

  float4 sreg[4], xreg[8];
#pragma unroll
  for (int p = 0; p < 4; p++)
    sreg[p] = *(const float4*)&sb[(size_t)(p * 16 + row16) * N_ + col4 * 4];
#pragma unroll
  for (int q = 0; q < 8; q++)
    xreg[q] = *(const float4*)&xg[(size_t)(q * 16 + row16) * N_ + col4 * 4];

  for (int ch = 0; ch < 8; ch++) {
#pragma unroll
    for (int p = 0; p < 4; p++) {
      uint2 v = make_uint2(pk(sreg[p].x, sreg[p].y), pk(sreg[p].z, sreg[p].w));
      *(uint2*)&sA[(p * 16 + row16) * 36 + col4 * 2] = v;
    }
#pragma unroll
    for (int q = 0; q < 8; q++) {
      uint2 v = make_uint2(pk(xreg[q].x, xreg[q].y), pk(xreg[q].z, xreg[q].w));
      *(uint2*)&sX[(q * 16 + row16) * 36 + col4 * 2] = v;
    }
    __syncthreads();
    if (ch < 7) {
      const int nb = (ch + 1) * 64;
#pragma unroll
      for (int p = 0; p < 4; p++)
        sreg[p] = *(const float4*)&sb[(size_t)(p * 16 + row16) * N_ + nb + col4 * 4];
#pragma unroll
      for (int q = 0; q < 8; q++)
        xreg[q] = *(const float4*)&xg[(size_t)(q * 16 + row16) * N_ + nb + col4 * 4];
    }
#pragma unroll
    for (int kk = 0; kk < 4; kk++) {
      U4 a0, a1, bf;
      a0.u = *(const uint4*)&sA[l31 * 36 + kk * 8 + lh * 4];
      a1.u = *(const uint4*)&sA[(32 + l31) * 36 + kk * 8 + lh * 4];
      bf.u = *(const uint4*)&sX[(wid * 32 + l31) * 36 + kk * 8 + lh * 4];
      acc[0] = __builtin_amdgcn_mfma_f32_32x32x16_bf16(a0.b, bf.b, acc[0], 0, 0, 0);
      acc[1] = __builtin_amdgcn_mfma_f32_32x32x16_bf16(a1.b, bf.b, acc[1], 0, 0, 0);
    }
    __syncthreads();
  }
  unsigned short* outp =
      wxp + ((size_t)(nt * B_ + b) * K_) * C_ + ct * 128 + wid * 32 + l31;
#pragma unroll
  for (int kt = 0; kt < 2; kt++)
#pragma unroll
    for (int r = 0; r < 16; r++) {
      int k = kt * 32 + (r & 3) + 8 * (r >> 2) + 4 * lh;
      outp[(size_t)k * C_] = bf16r(acc[kt][r]);
    }
}

// ---------------------------------------------------------------- kernel 4
// Sum 8 bf16 partials; nodes=(wx-wsum*a)/sigma/(wsum+eps); intra-norm; gsum.
__global__ void k_nodes(const unsigned short* __restrict__ wxp,
                        const float* __restrict__ wsum,
                        const float* __restrict__ anchor,
                        const float* __restrict__ invsig,
                        float* __restrict__ out0,
                        float* __restrict__ gsum) {
  const int k = blockIdx.x, b = blockIdx.y;
  const int tid = threadIdx.x;
  float wsv = wsum[b * K_ + k];
  float winv = 1.f / (wsv + 1e-9f);
  float vals[4];
  float local = 0.f;
#pragma unroll
  for (int r = 0; r < 4; r++) {
    int c = r * 128 + tid;
    float w = 0.f;
#pragma unroll
    for (int p = 0; p < 8; p++)
      w += fromhi(wxp[(((size_t)p * B_ + b) * K_ + k) * C_ + c]);
    float v = (w - wsv * anchor[k * C_ + c]) * invsig[k * C_ + c] * winv;
    vals[r] = v;
    local = fmaf(v, v, local);
  }
  float v = local;
#pragma unroll
  for (int off = 32; off; off >>= 1) v += __shfl_down(v, off);
  __shared__ float red[2];
  if ((tid & 63) == 0) red[tid >> 6] = v;
  __syncthreads();
  float sumsq = red[0] + red[1];
  float norm = sqrtf(sumsq);
  float scale = 1.f / fmaxf(norm, 1e-12f);
#pragma unroll
  for (int r = 0; r < 4; r++) {
    int c = r * 128 + tid;
    out0[((size_t)b * K_ + k) * C_ + c] = vals[r] * scale;
  }
  if (tid == 0) atomicAdd(&gsum[b], sumsq * scale * scale);
}

// ---------------------------------------------------------------- kernel 5
// Global L2 scale in place on out0 ([B][K*C] flat == reference (B,C,K)).
__global__ void k_final(float* __restrict__ out0,
                        const float* __restrict__ gsum) {
  for (int i = blockIdx.x * 256 + threadIdx.x; i < B_ * K_ * C_;
       i += gridDim.x * 256) {
    int b = i >> 15;  // K_*C_ = 32768
    out0[i] = out0[i] * (1.f / fmaxf(sqrtf(gsum[b]), 1e-12f));
  }
}

// ---------------------------------------------------------------- launch
extern "C" void kernel_launch(void* const* d_in, const int* in_sizes, int n_in,
                              void* d_out, int out_size, void* d_ws, size_t ws_size,
                              hipStream_t stream) {
  const float* x = (const float*)d_in[0];       // [B,C,H,W]
  const float* anchor = (const float*)d_in[1];  // [K,C]
  const float* sraw = (const float*)d_in[2];    // [K,C]
  float* out0 = (float*)d_out;                          // [B,C,K] flat
  float* soft = out0 + (size_t)B_ * C_ * K_;            // [B,K,N] (output 1)
  float* ws = (float*)d_ws;

  unsigned* pbig = (unsigned*)(ws + OFF_PBIG);
  float* constk = ws + OFF_CONST;
  float* invsig = ws + OFF_INVSIG;
  float* wsum = ws + OFF_WSUM;
  float* gsum = ws + OFF_GSUM;
  unsigned short* wxp = (unsigned short*)(ws + OFF_WXP);

  k_prep<<<K_, 256, 0, stream>>>(anchor, sraw, pbig, constk, invsig, wsum, gsum);
  k_dist<<<dim3(N_ / 128, B_), 256, 0, stream>>>(x, pbig, constk, soft, wsum);
  k_agg<<<dim3(C_ / 128, 8, B_), 256, 0, stream>>>(x, soft, wxp);
  k_nodes<<<dim3(K_, B_), 128, 0, stream>>>(wxp, wsum, anchor, invsig, out0,
                                            gsum);
  k_final<<<512, 256, 0, stream>>>(out0, gsum);
}